// Round 3
// baseline (97.856 us; speedup 1.0000x reference)
//
#include <hip/hip_runtime.h>
#include <hip/hip_bf16.h>

#define NN 8192
#define EPSF 1e-8f
#define LOG2E 1.4426950408889634f
#define LN2f 0.6931471805599453f
#define BLOCK 256
#define ROWS 4                                // rows per wave, processed simultaneously
#define ROWS_PER_BLOCK (ROWS * (BLOCK / 64))  // 16
#define NBLOCKS (NN / ROWS_PER_BLOCK)         // 512

// Scale factor folded into the staged a2 array:
//   yp = predict / 0.05 ;  a2 = yp * log2(e)  so that  exp(L - m) = exp2(a2*W - m')
#define A2SCALE (20.0f * LOG2E)

// ---------------------------------------------------------------------------
// Kernel 1: global min of true_similarity -> scal[0]
// ---------------------------------------------------------------------------
__global__ __launch_bounds__(1024) void prep_kernel(const float* __restrict__ yt,
                                                    float* __restrict__ scal) {
    __shared__ float red[16];
    int t = threadIdx.x;
    float mn = INFINITY;
    for (int i = t; i < NN; i += 1024) mn = fminf(mn, yt[i]);
#pragma unroll
    for (int m = 1; m < 64; m <<= 1) mn = fminf(mn, __shfl_xor(mn, m));
    if ((t & 63) == 0) red[t >> 6] = mn;
    __syncthreads();
    if (t < 16) {
        float v = red[t];
#pragma unroll
        for (int m = 1; m < 16; m <<= 1) v = fminf(v, __shfl_xor(v, m));
        if (t == 0) scal[0] = v;
    }
}

// ---------------------------------------------------------------------------
// Kernel 2: the O(N^2) pairwise loss. Each wave owns ROWS rows at once.
// For each row k:  negatives = { j : yt[k]-yt[j] > EPS }
//   m' = max(logit', max_j a2[j]*(yt[k]-yt[j]))   (scaled by log2 e)
//   sum = exp2(logit'-m') + sum_j exp2(a2[j]*W - m')
//   log_prob = (logit'-m')*ln2 - log(sum)
// Accumulate (sum of log_prob over valid rows, count) via one atomic per block.
// ---------------------------------------------------------------------------
__global__ __launch_bounds__(BLOCK) void pro_main(const float* __restrict__ yt_g,
                                                  const float* __restrict__ pred_g,
                                                  const float* __restrict__ scal,
                                                  float* __restrict__ acc) {
    __shared__ float4 yt_s[NN / 4];   // 32 KB
    __shared__ float4 a2_s[NN / 4];   // 32 KB   (total 64 KB static LDS)

    const int t = threadIdx.x;
    const float4* ytg4 = (const float4*)yt_g;
    const float4* pdg4 = (const float4*)pred_g;
    for (int i = t; i < NN / 4; i += BLOCK) {
        yt_s[i] = ytg4[i];
        float4 p = pdg4[i];
        p.x *= A2SCALE; p.y *= A2SCALE; p.z *= A2SCALE; p.w *= A2SCALE;
        a2_s[i] = p;
    }
    __syncthreads();

    const float yt_min = scal[0];
    const int wave = t >> 6, lane = t & 63;
    const int row0 = blockIdx.x * ROWS_PER_BLOCK + wave * ROWS;

    const float* yts = (const float*)yt_s;
    const float* a2s = (const float*)a2_s;

    float x[ROWS], lp[ROWS], M[ROWS], vld[ROWS];
#pragma unroll
    for (int r = 0; r < ROWS; ++r) {
        x[r] = yts[row0 + r];
        float w = x[r] - yt_min;              // == weight_k (same f32 sub as ref)
        vld[r] = (w > EPSF) ? 1.0f : 0.0f;    // row_valid
        lp[r] = a2s[row0 + r] * w;            // logit_pos * log2(e)
        M[r] = -INFINITY;
    }

    // ---- pass 1: masked max of scaled negative logits ----
    for (int i = 0; i < NN / 256; ++i) {
        float4 y4 = yt_s[i * 64 + lane];
        float4 a4 = a2_s[i * 64 + lane];
#pragma unroll
        for (int r = 0; r < ROWS; ++r) {
            float W0 = x[r] - y4.x; float L0 = a4.x * W0; M[r] = fmaxf(M[r], (W0 > EPSF) ? L0 : -INFINITY);
            float W1 = x[r] - y4.y; float L1 = a4.y * W1; M[r] = fmaxf(M[r], (W1 > EPSF) ? L1 : -INFINITY);
            float W2 = x[r] - y4.z; float L2 = a4.z * W2; M[r] = fmaxf(M[r], (W2 > EPSF) ? L2 : -INFINITY);
            float W3 = x[r] - y4.w; float L3 = a4.w * W3; M[r] = fmaxf(M[r], (W3 > EPSF) ? L3 : -INFINITY);
        }
    }
#pragma unroll
    for (int r = 0; r < ROWS; ++r) {
#pragma unroll
        for (int m = 1; m < 64; m <<= 1) M[r] = fmaxf(M[r], __shfl_xor(M[r], m));
        M[r] = fmaxf(M[r], lp[r]);            // m' (scaled running max incl. positive)
    }

    // ---- pass 2: masked exp2 sum ----
    float s[ROWS];
#pragma unroll
    for (int r = 0; r < ROWS; ++r) s[r] = 0.0f;

    for (int i = 0; i < NN / 256; ++i) {
        float4 y4 = yt_s[i * 64 + lane];
        float4 a4 = a2_s[i * 64 + lane];
#pragma unroll
        for (int r = 0; r < ROWS; ++r) {
            float W0 = x[r] - y4.x; float t0 = __builtin_fmaf(a4.x, W0, -M[r]); s[r] += exp2f((W0 > EPSF) ? t0 : -INFINITY);
            float W1 = x[r] - y4.y; float t1 = __builtin_fmaf(a4.y, W1, -M[r]); s[r] += exp2f((W1 > EPSF) ? t1 : -INFINITY);
            float W2 = x[r] - y4.z; float t2 = __builtin_fmaf(a4.z, W2, -M[r]); s[r] += exp2f((W2 > EPSF) ? t2 : -INFINITY);
            float W3 = x[r] - y4.w; float t3 = __builtin_fmaf(a4.w, W3, -M[r]); s[r] += exp2f((W3 > EPSF) ? t3 : -INFINITY);
        }
    }
#pragma unroll
    for (int r = 0; r < ROWS; ++r) {
#pragma unroll
        for (int m = 1; m < 64; m <<= 1) s[r] += __shfl_xor(s[r], m);
    }

    // ---- per-row epilogue (computed redundantly on all lanes) ----
    float wtot = 0.0f, wcnt = 0.0f;
#pragma unroll
    for (int r = 0; r < ROWS; ++r) {
        float lpm = lp[r] - M[r];             // logit' - m'  (<= 0)
        float sum = exp2f(lpm) + s[r];        // >= 1 for valid rows
        float logp = lpm * LN2f - __logf(sum);
        wtot += vld[r] * logp;
        wcnt += vld[r];
    }

    // ---- block reduction: 4 waves -> 1 atomic pair ----
    __syncthreads();                          // all LDS reads of yt_s/a2_s done
    float* wred = (float*)yt_s;               // reuse LDS
    if (lane == 0) { wred[wave * 2] = wtot; wred[wave * 2 + 1] = wcnt; }
    __syncthreads();
    if (t == 0) {
        float bt = 0.0f, bc = 0.0f;
        for (int w2 = 0; w2 < BLOCK / 64; ++w2) { bt += wred[w2 * 2]; bc += wred[w2 * 2 + 1]; }
        atomicAdd(&acc[0], bt);
        atomicAdd(&acc[1], bc);
    }
}

// ---------------------------------------------------------------------------
// Kernel 3: final scalar
// ---------------------------------------------------------------------------
__global__ void finalize_kernel(const float* __restrict__ acc, float* __restrict__ out) {
    out[0] = (acc[1] > 0.0f) ? (-acc[0] / acc[1]) : 0.0f;
}

extern "C" void kernel_launch(void* const* d_in, const int* in_sizes, int n_in,
                              void* d_out, int out_size, void* d_ws, size_t ws_size,
                              hipStream_t stream) {
    const float* pred = (const float*)d_in[0];  // predict_similarity
    const float* yt   = (const float*)d_in[1];  // true_similarity

    float* scal = (float*)d_ws;      // scal[0] = yt_min
    float* acc  = scal + 1;          // acc[0] = total, acc[1] = count

    hipMemsetAsync(acc, 0, 2 * sizeof(float), stream);
    prep_kernel<<<1, 1024, 0, stream>>>(yt, scal);
    pro_main<<<NBLOCKS, BLOCK, 0, stream>>>(yt, pred, scal, acc);
    finalize_kernel<<<1, 1, 0, stream>>>(acc, (float*)d_out);
}

// Round 4
// 93.022 us; speedup vs baseline: 1.0520x; 1.0520x over previous
//
#include <hip/hip_runtime.h>
#include <hip/hip_bf16.h>

#define NN 8192
#define EPSF 1e-8f
#define LOG2E 1.4426950408889634f
#define LN2f 0.6931471805599453f
#define BLOCK 256
#define ROWS 4                                // rows per wave
#define ROWS_PER_BLOCK (ROWS * (BLOCK / 64))  // 16
#define RG (NN / ROWS_PER_BLOCK)              // 512 row-groups
#define CHUNKS 4
#define CH (NN / CHUNKS)                      // 2048 j-elements per chunk

// a2 = (pred/0.05)*log2(e) so exp(L-m) = exp2(a2*W - m')
#define A2SCALE (20.0f * LOG2E)

// ---------------------------------------------------------------------------
// Kernel 1: chunk-partial masked max + logsumexp.
// Block (rg, c): rows [rg*16, rg*16+16) x j in [c*2048, (c+1)*2048).
// Writes partial[c][row] = (M_c, s_c) where
//   M_c = max_{j in chunk, valid} a2[j]*(x-yt[j])     (log2-scaled)
//   s_c = sum_{j in chunk, valid} exp2(a2[j]*(x-yt[j]) - M_c)
// No atomics, no prior zeroing needed (pure overwrite).
// ---------------------------------------------------------------------------
__global__ __launch_bounds__(BLOCK) void pro_main(const float* __restrict__ yt_g,
                                                  const float* __restrict__ pred_g,
                                                  float2* __restrict__ partial) {
    __shared__ float4 yt_s[CH / 4];   // 8 KB
    __shared__ float4 a2_s[CH / 4];   // 8 KB  (16 KB total -> ~8 blocks/CU)

    const int t = threadIdx.x;
    const int rg = blockIdx.x >> 2;   // row-group
    const int c  = blockIdx.x & 3;    // j-chunk

    const float4* ytg4 = (const float4*)(yt_g + c * CH);
    const float4* pdg4 = (const float4*)(pred_g + c * CH);
    for (int i = t; i < CH / 4; i += BLOCK) {
        yt_s[i] = ytg4[i];
        float4 p = pdg4[i];
        p.x *= A2SCALE; p.y *= A2SCALE; p.z *= A2SCALE; p.w *= A2SCALE;
        a2_s[i] = p;
    }
    __syncthreads();

    const int wave = t >> 6, lane = t & 63;
    const int row0 = rg * ROWS_PER_BLOCK + wave * ROWS;

    float x[ROWS], M[ROWS];
#pragma unroll
    for (int r = 0; r < ROWS; ++r) {
        x[r] = yt_g[row0 + r];        // broadcast read, L2-hit
        M[r] = -INFINITY;
    }

    // ---- pass 1: masked max of scaled negative logits over this chunk ----
    for (int i = 0; i < CH / 256; ++i) {
        float4 y4 = yt_s[i * 64 + lane];
        float4 a4 = a2_s[i * 64 + lane];
#pragma unroll
        for (int r = 0; r < ROWS; ++r) {
            float W0 = x[r] - y4.x; float L0 = a4.x * W0; M[r] = fmaxf(M[r], (W0 > EPSF) ? L0 : -INFINITY);
            float W1 = x[r] - y4.y; float L1 = a4.y * W1; M[r] = fmaxf(M[r], (W1 > EPSF) ? L1 : -INFINITY);
            float W2 = x[r] - y4.z; float L2 = a4.z * W2; M[r] = fmaxf(M[r], (W2 > EPSF) ? L2 : -INFINITY);
            float W3 = x[r] - y4.w; float L3 = a4.w * W3; M[r] = fmaxf(M[r], (W3 > EPSF) ? L3 : -INFINITY);
        }
    }
#pragma unroll
    for (int r = 0; r < ROWS; ++r) {
#pragma unroll
        for (int m = 1; m < 64; m <<= 1) M[r] = fmaxf(M[r], __shfl_xor(M[r], m));
    }

    // ---- pass 2: masked exp2 sum (chunk-local max as stabilizer) ----
    float s[ROWS] = {0.f, 0.f, 0.f, 0.f};
    for (int i = 0; i < CH / 256; ++i) {
        float4 y4 = yt_s[i * 64 + lane];
        float4 a4 = a2_s[i * 64 + lane];
#pragma unroll
        for (int r = 0; r < ROWS; ++r) {
            float W0 = x[r] - y4.x; float t0 = __builtin_fmaf(a4.x, W0, -M[r]); s[r] += exp2f((W0 > EPSF) ? t0 : -INFINITY);
            float W1 = x[r] - y4.y; float t1 = __builtin_fmaf(a4.y, W1, -M[r]); s[r] += exp2f((W1 > EPSF) ? t1 : -INFINITY);
            float W2 = x[r] - y4.z; float t2 = __builtin_fmaf(a4.z, W2, -M[r]); s[r] += exp2f((W2 > EPSF) ? t2 : -INFINITY);
            float W3 = x[r] - y4.w; float t3 = __builtin_fmaf(a4.w, W3, -M[r]); s[r] += exp2f((W3 > EPSF) ? t3 : -INFINITY);
        }
    }
#pragma unroll
    for (int r = 0; r < ROWS; ++r) {
#pragma unroll
        for (int m = 1; m < 64; m <<= 1) s[r] += __shfl_xor(s[r], m);
    }

    if (lane == 0) {
#pragma unroll
        for (int r = 0; r < ROWS; ++r) partial[c * NN + row0 + r] = make_float2(M[r], s[r]);
    }
}

// ---------------------------------------------------------------------------
// Kernel 2: global min of yt, per-row combine of the 4 chunk partials,
// epilogue, and final scalar. One block of 1024.
//   M = max(lp, max_c M_c); sum = exp2(lp-M) + sum_c s_c*exp2(M_c-M)
//   log_prob = (lp-M)*ln2 - log(sum)
// Chunks with no valid pairs carry (-inf, 0): 0*exp2(-inf) = 0, harmless.
// ---------------------------------------------------------------------------
__global__ __launch_bounds__(1024) void finalize(const float* __restrict__ yt,
                                                 const float* __restrict__ pred,
                                                 const float2* __restrict__ partial,
                                                 float* __restrict__ out) {
    __shared__ float redm[16];
    __shared__ float2 red2[16];
    __shared__ float bmin;
    const int t = threadIdx.x, lane = t & 63, wave = t >> 6;

    // global min of yt
    float mn = INFINITY;
    for (int i = t; i < NN; i += 1024) mn = fminf(mn, yt[i]);
#pragma unroll
    for (int m = 1; m < 64; m <<= 1) mn = fminf(mn, __shfl_xor(mn, m));
    if (lane == 0) redm[wave] = mn;
    __syncthreads();
    if (t == 0) {
        float v = redm[0];
        for (int i = 1; i < 16; ++i) v = fminf(v, redm[i]);
        bmin = v;
    }
    __syncthreads();
    const float yt_min = bmin;

    float wtot = 0.f, wcnt = 0.f;
    for (int row = t; row < NN; row += 1024) {
        float x = yt[row];
        float w = x - yt_min;                 // == weight_k (max masked gap)
        float a2 = pred[row] * A2SCALE;
        float lp = a2 * w;                    // logit_pos, log2-scaled
        float2 pc[CHUNKS];
        float M = lp;
#pragma unroll
        for (int c = 0; c < CHUNKS; ++c) {
            pc[c] = partial[c * NN + row];
            M = fmaxf(M, pc[c].x);
        }
        float sum = exp2f(lp - M);
#pragma unroll
        for (int c = 0; c < CHUNKS; ++c) sum += pc[c].y * exp2f(pc[c].x - M);
        float logp = (lp - M) * LN2f - __logf(sum);
        if (w > EPSF) { wtot += logp; wcnt += 1.f; }
    }
#pragma unroll
    for (int m = 1; m < 64; m <<= 1) { wtot += __shfl_xor(wtot, m); wcnt += __shfl_xor(wcnt, m); }
    if (lane == 0) red2[wave] = make_float2(wtot, wcnt);
    __syncthreads();
    if (t == 0) {
        float bt = 0.f, bc = 0.f;
        for (int i = 0; i < 16; ++i) { bt += red2[i].x; bc += red2[i].y; }
        out[0] = (bc > 0.f) ? (-bt / bc) : 0.f;
    }
}

extern "C" void kernel_launch(void* const* d_in, const int* in_sizes, int n_in,
                              void* d_out, int out_size, void* d_ws, size_t ws_size,
                              hipStream_t stream) {
    const float* pred = (const float*)d_in[0];  // predict_similarity
    const float* yt   = (const float*)d_in[1];  // true_similarity

    float2* partial = (float2*)d_ws;            // [CHUNKS][NN], 256 KB, overwritten fully

    pro_main<<<RG * CHUNKS, BLOCK, 0, stream>>>(yt, pred, partial);
    finalize<<<1, 1024, 0, stream>>>(yt, pred, partial, (float*)d_out);
}